// Round 10
// baseline (484.797 us; speedup 1.0000x reference)
//
#include <hip/hip_runtime.h>
#include <math.h>

// ---------------- helpers ----------------
static __device__ __forceinline__ float lrelu(float x){ return fmaxf(x, 0.2f*x); }
static __device__ __forceinline__ float eluf(float x){ return x > 0.f ? x : __expf(x)-1.f; }
static __device__ __forceinline__ float wred_sum(float v){
  v += __shfl_xor(v, 32); v += __shfl_xor(v, 16); v += __shfl_xor(v, 8);
  v += __shfl_xor(v, 4);  v += __shfl_xor(v, 2);  v += __shfl_xor(v, 1);
  return v;
}
static __device__ __forceinline__ unsigned short f2bf(float f){
  unsigned int u = __float_as_uint(f);
  unsigned int r = (u + 0x7FFFu + ((u>>16)&1u)) >> 16;   // round-nearest-even
  return (unsigned short)r;
}
static __device__ __forceinline__ float bflo(unsigned int u){ return __uint_as_float(u<<16); }
static __device__ __forceinline__ float bfhi(unsigned int u){ return __uint_as_float(u & 0xFFFF0000u); }

typedef __attribute__((ext_vector_type(8))) short short8;   // 8 bf16 = 4 VGPR
typedef __attribute__((ext_vector_type(4))) float f32x4;

// ---------------- bucketed CSR build (bucket = dst>>7) ----------------
#define DETECT_IS64(ei_, s_is64_) \
  if (threadIdx.x < 64){ \
    int w_ = ((const int*)(ei_))[2*threadIdx.x + 1]; \
    unsigned long long b_ = __ballot(w_ != 0); \
    if (threadIdx.x == 0) s_is64_ = (b_ == 0ull); \
  } \
  __syncthreads();

__global__ __launch_bounds__(256) void k_bhist(const void* __restrict__ ei,
    int* __restrict__ gbcnt, int E, int NB){
  extern __shared__ int lcnt[];
  __shared__ int s_is64;
  for (int i=threadIdx.x; i<NB; i+=256) lcnt[i]=0;
  DETECT_IS64(ei, s_is64)
  int stride = gridDim.x*256;
  if (s_is64){
    const long long* p = (const long long*)ei;
    for (int e = blockIdx.x*256 + threadIdx.x; e < E; e += stride)
      atomicAdd(&lcnt[((int)p[(size_t)E+e])>>7], 1);
  } else {
    const int* p = (const int*)ei;
    for (int e = blockIdx.x*256 + threadIdx.x; e < E; e += stride)
      atomicAdd(&lcnt[p[(size_t)E+e]>>7], 1);
  }
  __syncthreads();
  for (int i=threadIdx.x; i<NB; i+=256){
    int c = lcnt[i];
    if (c) atomicAdd(&gbcnt[i], c);
  }
}

__global__ __launch_bounds__(256) void k_bscan(const int* __restrict__ gbcnt,
    int* __restrict__ gbbase, int* __restrict__ gcursor, int NB){
  __shared__ int sh[256];
  __shared__ int carry;
  int t = threadIdx.x;
  if (t==0) carry = 0;
  __syncthreads();
  for (int base=0; base<NB; base+=256){
    int idx = base+t;
    int v = (idx<NB)? gbcnt[idx] : 0;
    sh[t]=v; __syncthreads();
    for (int off=1; off<256; off<<=1){
      int add = (t>=off)? sh[t-off] : 0;
      __syncthreads();
      sh[t]+=add;
      __syncthreads();
    }
    int excl = sh[t]-v+carry;
    if (idx<NB){ gbbase[idx]=excl; gcursor[idx]=excl; }
    __syncthreads();
    if (t==0) carry += sh[255];
    __syncthreads();
  }
}

// ---- FUSED: bscatter (blocks [0,GS)) || mgemm1 (blocks [GS, GS+G1)) -------
#define BS_ITEMS 16
__global__ __launch_bounds__(256) void k_scat_gemm1(
    const void* __restrict__ ei, int* __restrict__ gcursor,
    unsigned int* __restrict__ ebuf, int E, int NB, int GS,
    const float* __restrict__ x, const unsigned short* __restrict__ wf,
    const float* __restrict__ atts, const float* __restrict__ attd,
    unsigned short* __restrict__ hb, float* __restrict__ as_, float* __restrict__ ad_,
    int N){
  __shared__ __align__(16) unsigned char smem[50176];
  __shared__ int s_is64;
  int t = threadIdx.x;
  if ((int)blockIdx.x < GS){
    // ---------------- scatter role ----------------
    int* lcnt  = (int*)smem;
    int* lbase = lcnt + NB;
    for (int i=t; i<NB; i+=256) lcnt[i]=0;
    DETECT_IS64(ei, s_is64)
    bool is64 = s_is64 != 0;
    int base = blockIdx.x*(256*BS_ITEMS);
    unsigned int ent[BS_ITEMS]; int bk[BS_ITEMS];
    #pragma unroll
    for (int i=0;i<BS_ITEMS;i++){
      int e = base + i*256 + t;
      if (e < E){
        int s, d;
        if (is64){ const long long* p=(const long long*)ei; s=(int)p[e]; d=(int)p[(size_t)E+e]; }
        else     { const int* p=(const int*)ei;            s=p[e];      d=p[(size_t)E+e]; }
        int b = d>>7;
        bk[i] = b;
        ent[i] = (unsigned int)s | ((unsigned int)(d & 127) << 25);
        atomicAdd(&lcnt[b], 1);
      } else bk[i] = -1;
    }
    __syncthreads();
    for (int i=t; i<NB; i+=256){
      int c = lcnt[i];
      lbase[i] = c ? atomicAdd(&gcursor[i], c) : 0;
    }
    __syncthreads();
    for (int i=t; i<NB; i+=256) lcnt[i]=0;  // reuse as cursor
    __syncthreads();
    #pragma unroll
    for (int i=0;i<BS_ITEMS;i++){
      if (bk[i] >= 0){
        int pos = lbase[bk[i]] + atomicAdd(&lcnt[bk[i]], 1);
        ebuf[pos] = ent[i];
      }
    }
  } else {
    // ---------------- mgemm1 role ----------------
    unsigned short* xs  = (unsigned short*)smem;              // 64*136
    unsigned short* wsm = (unsigned short*)(smem + 64*136*2); // 2048*8
    int r0 = ((int)blockIdx.x - GS)*64;
    { // stage W frags: 2048 uint4 (32 KB)
      const uint4* src = (const uint4*)wf;
      uint4* dst = (uint4*)wsm;
      #pragma unroll
      for (int i=0;i<8;i++) dst[t + i*256] = src[t + i*256];
    }
    { // stage x tile (fp32 -> bf16)
      #pragma unroll
      for (int i=0;i<4;i++){
        int idx = t + i*256;
        int row = idx>>4, k8 = (idx&15)*8;
        int gr = r0 + row;
        float4 v0 = make_float4(0.f,0.f,0.f,0.f), v1 = v0;
        if (gr < N){
          v0 = *(const float4*)&x[(size_t)gr*128 + k8];
          v1 = *(const float4*)&x[(size_t)gr*128 + k8 + 4];
        }
        union { unsigned short us[8]; uint4 u; } pk;
        pk.us[0]=f2bf(v0.x); pk.us[1]=f2bf(v0.y); pk.us[2]=f2bf(v0.z); pk.us[3]=f2bf(v0.w);
        pk.us[4]=f2bf(v1.x); pk.us[5]=f2bf(v1.y); pk.us[6]=f2bf(v1.z); pk.us[7]=f2bf(v1.w);
        *(uint4*)&xs[row*136 + k8] = pk.u;
      }
    }
    __syncthreads();
    int w = t>>6, lane = t&63, lm = lane&15, q = lane>>4;
    int rt0 = (w&1)*2;
    int ct0 = (w>>1)*4;
    f32x4 acc[2][4];
    #pragma unroll
    for (int a=0;a<2;a++)
      #pragma unroll
      for (int c=0;c<4;c++) acc[a][c] = (f32x4){0.f,0.f,0.f,0.f};
    #pragma unroll
    for (int ks=0;ks<4;ks++){
      short8 a0 = *(const short8*)&xs[( rt0   *16 + lm)*136 + ks*32 + q*8];
      short8 a1 = *(const short8*)&xs[((rt0+1)*16 + lm)*136 + ks*32 + q*8];
      #pragma unroll
      for (int c=0;c<4;c++){
        short8 b = *(const short8*)&wsm[((ks*8 + ct0 + c)*64 + lane)*8];
        acc[0][c] = __builtin_amdgcn_mfma_f32_16x16x32_bf16(a0, b, acc[0][c], 0,0,0);
        acc[1][c] = __builtin_amdgcn_mfma_f32_16x16x32_bf16(a1, b, acc[1][c], 0,0,0);
      }
    }
    __syncthreads();   // xs becomes C-tile
    // C/D layout: col = lane&15, row = (lane>>4)*4 + reg (guide §3, m89/m91)
    #pragma unroll
    for (int rl=0;rl<2;rl++)
      #pragma unroll
      for (int c=0;c<4;c++)
        #pragma unroll
        for (int r=0;r<4;r++)
          xs[((rt0+rl)*16 + q*4 + r)*136 + (ct0+c)*16 + lm] = f2bf(acc[rl][c][r]);
    __syncthreads();
    { // hb writes
      #pragma unroll
      for (int i=0;i<4;i++){
        int idx = t + i*256;
        int row = idx>>4, c8 = (idx&15)*8;
        int gr = r0 + row;
        if (gr < N)
          *(uint4*)&hb[(size_t)gr*128 + c8] = *(const uint4*)&xs[row*136 + c8];
      }
    }
    { // fused attention dots
      int row = t>>2, h = t&3;
      int gr = r0 + row;
      if (gr < N){
        const unsigned short* hr = &xs[row*136 + h*32];
        const float* sa = atts + h*32;
        const float* da = attd + h*32;
        float ss = 0.f, dd = 0.f;
        #pragma unroll
        for (int o=0;o<32;o+=8){
          uint4 v = *(const uint4*)&hr[o];
          float hv[8] = { bflo(v.x),bfhi(v.x),bflo(v.y),bfhi(v.y),
                          bflo(v.z),bfhi(v.z),bflo(v.w),bfhi(v.w) };
          #pragma unroll
          for (int m=0;m<8;m++){ ss += hv[m]*sa[o+m]; dd += hv[m]*da[o+m]; }
        }
        as_[gr*4+h] = ss; ad_[gr*4+h] = dd;
      }
    }
  }
}

__global__ __launch_bounds__(256) void k_bcsr(const unsigned int* __restrict__ ebuf,
    const int* __restrict__ gbbase, const int* __restrict__ gbcnt,
    int* __restrict__ rp, int* __restrict__ csr, int N, int NB, int E){
  __shared__ int lcnt[128];
  __shared__ int lexc[128];
  __shared__ int lcur[128];
  __shared__ int sc[256];
  int b = blockIdx.x, t = threadIdx.x;
  int d0 = b<<7;
  int R = N - d0; if (R > 128) R = 128;
  if (t < 128){ lcnt[t]=0; lcur[t]=0; }
  __syncthreads();
  int base = gbbase[b], cnt = gbcnt[b];
  for (int i=t; i<cnt; i+=256){
    unsigned int e = ebuf[base+i];
    atomicAdd(&lcnt[e>>25], 1);
  }
  __syncthreads();
  int v = (t<128)? lcnt[t] : 0;
  sc[t]=v; __syncthreads();
  for (int off=1; off<128; off<<=1){
    int add = (t>=off)? sc[t-off] : 0;
    __syncthreads();
    sc[t]+=add;
    __syncthreads();
  }
  if (t<128) lexc[t] = sc[t]-v;
  __syncthreads();
  if (t < R) rp[d0+t] = base + lexc[t];
  if (b == NB-1 && t == 0) rp[N] = E;
  for (int i=t; i<cnt; i+=256){
    unsigned int e = ebuf[base+i];
    int dl = e>>25;
    int pos = base + lexc[dl] + atomicAdd(&lcur[dl], 1);
    csr[pos] = (int)(e & 0x1FFFFFFu);
  }
}

// ------- W1 pre-pack into MFMA B-fragment order (bf16), once per call ------
__global__ void k_wprep(const float* __restrict__ W1, unsigned short* __restrict__ wf1){
  int e = blockIdx.x*256 + threadIdx.x;
  if (e < 2048){
    int lane = e&63, ct = (e>>6)&7, ks = e>>9;
    int q = lane>>4, n = lane&15;
    union { unsigned short us[8]; uint4 u; } pk;
    #pragma unroll
    for (int j=0;j<8;j++)
      pk.us[j] = f2bf(W1[(ks*32 + q*8 + j)*128 + ct*16 + n]);
    *(uint4*)&wf1[(size_t)e*8] = pk.u;
  }
}

// ---------------- aggregation ---------------------------------------------
// Layer 1: H=4,O=32. 32 edges/iter, exp-deduplicated, 8 gathers in flight.
// FUSED layer-2 GEMM epilogue: after the xor-reduce every lane holds its
// 8-col slice of the layer-1 output row; ELU in-register, dot with fp32 W2
// (L1-resident), li-xor-reduce -> hb2 bf16 + layer-2 att terms. Deletes
// k_mgemm2 and the 51 MB xb round-trip.
__global__ __launch_bounds__(256) void k_agg1(const int* __restrict__ rp, const int* __restrict__ csr,
    const float* __restrict__ as_, const float* __restrict__ ad_,
    const uint4* __restrict__ hb4, const float* __restrict__ bias,
    const float* __restrict__ W2, const float* __restrict__ atts2,
    const float* __restrict__ attd2,
    unsigned short* __restrict__ hb2, float* __restrict__ as2_, float* __restrict__ ad2_,
    int N){
  int n = blockIdx.x*4 + (threadIdx.x>>6);
  if (n >= N) return;
  int lane = threadIdx.x & 63;
  int eslot = lane>>2, ehead = lane&3;       // exp duty: 16 edge-slots x 4 heads
  int grp = lane>>4, li = lane&15, ghead = li>>2;  // gather duty
  int start = rp[n], end = rp[n+1];
  float adh_e = ad_[n*4+ehead];
  float w_self_e = __expf(fminf(lrelu(as_[n*4+ehead] + adh_e), 80.f));
  float l = (eslot == 0) ? w_self_e : 0.f;
  float a[8];
  #pragma unroll
  for (int k=0;k<8;k++) a[k]=0.f;
  { // self-loop row first
    float w = __shfl(w_self_e, ghead);
    if (grp == 0){
      uint4 v = hb4[(size_t)n*16 + li];
      a[0]+=w*bflo(v.x); a[1]+=w*bfhi(v.x); a[2]+=w*bflo(v.y); a[3]+=w*bfhi(v.y);
      a[4]+=w*bflo(v.z); a[5]+=w*bfhi(v.z); a[6]+=w*bflo(v.w); a[7]+=w*bfhi(v.w);
    }
  }
  for (int i0 = start; i0 < end; i0 += 32){
    int ei0 = i0 + eslot, ei1 = i0 + 16 + eslot;
    int s0 = -1, s1 = -1; float w0 = 0.f, w1 = 0.f;
    if (ei0 < end){
      s0 = csr[ei0];
      w0 = __expf(fminf(lrelu(as_[s0*4+ehead] + adh_e), 80.f));
      l += w0;
    }
    if (ei1 < end){
      s1 = csr[ei1];
      w1 = __expf(fminf(lrelu(as_[s1*4+ehead] + adh_e), 80.f));
      l += w1;
    }
    #pragma unroll
    for (int r=0;r<4;r++){
      int srclane = ((r*4+grp)<<2) | ghead;
      int   s2 = __shfl(s0, srclane);
      float w2 = __shfl(w0, srclane);
      int   s3 = __shfl(s1, srclane);
      float w3 = __shfl(w1, srclane);
      if (s2 >= 0){
        uint4 v = hb4[(size_t)s2*16 + li];
        a[0]+=w2*bflo(v.x); a[1]+=w2*bfhi(v.x); a[2]+=w2*bflo(v.y); a[3]+=w2*bfhi(v.y);
        a[4]+=w2*bflo(v.z); a[5]+=w2*bfhi(v.z); a[6]+=w2*bflo(v.w); a[7]+=w2*bfhi(v.w);
      }
      if (s3 >= 0){
        uint4 v = hb4[(size_t)s3*16 + li];
        a[0]+=w3*bflo(v.x); a[1]+=w3*bfhi(v.x); a[2]+=w3*bflo(v.y); a[3]+=w3*bfhi(v.y);
        a[4]+=w3*bflo(v.z); a[5]+=w3*bfhi(v.z); a[6]+=w3*bflo(v.w); a[7]+=w3*bfhi(v.w);
      }
    }
  }
  l += __shfl_xor(l,4); l += __shfl_xor(l,8); l += __shfl_xor(l,16); l += __shfl_xor(l,32);
  #pragma unroll
  for (int msk=16; msk<64; msk<<=1){
    #pragma unroll
    for (int k=0;k<8;k++) a[k] += __shfl_xor(a[k], msk);
  }
  // every lane now holds full sums for its li's 8 cols
  float denom = __shfl(l, ghead);
  float invh = 1.f/denom;
  float r[8];
  #pragma unroll
  for (int k=0;k<8;k++) r[k] = eluf(a[k]*invh + bias[li*8+k]);
  // fused layer-2 GEMM: out cols grp*8..grp*8+7; lane covers ks li*8..li*8+7
  float p[8];
  #pragma unroll
  for (int c=0;c<8;c++) p[c]=0.f;
  #pragma unroll
  for (int j=0;j<8;j++){
    const float4* wrow = (const float4*)&W2[(li*8+j)*32 + grp*8];
    float4 w0 = wrow[0], w1 = wrow[1];
    float rv = r[j];
    p[0]+=rv*w0.x; p[1]+=rv*w0.y; p[2]+=rv*w0.z; p[3]+=rv*w0.w;
    p[4]+=rv*w1.x; p[5]+=rv*w1.y; p[6]+=rv*w1.z; p[7]+=rv*w1.w;
  }
  #pragma unroll
  for (int msk=1; msk<16; msk<<=1){
    #pragma unroll
    for (int c=0;c<8;c++) p[c] += __shfl_xor(p[c], msk);
  }
  if (li == 0){ // one lane per grp writes 8 bf16 cols
    union { unsigned short us[8]; uint4 v; } pk2;
    #pragma unroll
    for (int c=0;c<8;c++) pk2.us[c] = f2bf(p[c]);
    *(uint4*)&hb2[(size_t)n*32 + grp*8] = pk2.v;
  }
  { // layer-2 att terms: head h2 = grp>>1, offset (grp&1)*8
    int h2h = grp>>1, ob = (grp&1)*8;
    const float* sa = atts2 + h2h*16 + ob;
    const float* da = attd2 + h2h*16 + ob;
    float ss=0.f, dd=0.f;
    #pragma unroll
    for (int c=0;c<8;c++){ ss += p[c]*sa[c]; dd += p[c]*da[c]; }
    ss += __shfl_xor(ss, 16); dd += __shfl_xor(dd, 16);
    if (li == 0 && (grp&1)==0){
      as2_[n*2 + h2h] = ss;
      ad2_[n*2 + h2h] = dd;
    }
  }
}

// Layer 2: H=2,O=16. 64 edges/iter, exp-dedup. Fused layer-3 GEMM epilogue;
// writes packed float4(h3.x, h3.y, as3, ad3) so agg3 gathers ONE 16B load/edge.
__global__ __launch_bounds__(256) void k_agg2(const int* __restrict__ rp, const int* __restrict__ csr,
    const float* __restrict__ as_, const float* __restrict__ ad_,
    const uint4* __restrict__ hb4, const float* __restrict__ bias,
    const float* __restrict__ W3, const float* __restrict__ atts3,
    const float* __restrict__ attd3,
    float4* __restrict__ pk4, int N){
  int n = blockIdx.x*4 + (threadIdx.x>>6);
  if (n >= N) return;
  int lane = threadIdx.x & 63;
  int eslot = lane>>1, ehead = lane&1;       // 32 edge-slots x 2 heads
  int grp = lane>>2, li = lane&3, ghead = li>>1;
  int start = rp[n], end = rp[n+1];
  float adh_e = ad_[n*2+ehead];
  float w_self_e = __expf(fminf(lrelu(as_[n*2+ehead] + adh_e), 80.f));
  float l = (eslot == 0) ? w_self_e : 0.f;
  float a[8];
  #pragma unroll
  for (int k=0;k<8;k++) a[k]=0.f;
  { // self-loop row first
    float w = __shfl(w_self_e, ghead);
    if (grp == 0){
      uint4 v = hb4[(size_t)n*4 + li];
      a[0]+=w*bflo(v.x); a[1]+=w*bfhi(v.x); a[2]+=w*bflo(v.y); a[3]+=w*bfhi(v.y);
      a[4]+=w*bflo(v.z); a[5]+=w*bfhi(v.z); a[6]+=w*bflo(v.w); a[7]+=w*bfhi(v.w);
    }
  }
  for (int i0 = start; i0 < end; i0 += 64){
    int ei0 = i0 + eslot, ei1 = i0 + 32 + eslot;
    int s0 = -1, s1 = -1; float w0 = 0.f, w1 = 0.f;
    if (ei0 < end){
      s0 = csr[ei0];
      w0 = __expf(fminf(lrelu(as_[s0*2+ehead] + adh_e), 80.f));
      l += w0;
    }
    if (ei1 < end){
      s1 = csr[ei1];
      w1 = __expf(fminf(lrelu(as_[s1*2+ehead] + adh_e), 80.f));
      l += w1;
    }
    #pragma unroll
    for (int r=0;r<2;r++){
      int srclane = ((r*16+grp)<<1) | ghead;
      int   s2 = __shfl(s0, srclane);
      float w2 = __shfl(w0, srclane);
      int   s3 = __shfl(s1, srclane);
      float w3 = __shfl(w1, srclane);
      if (s2 >= 0){
        uint4 v = hb4[(size_t)s2*4 + li];
        a[0]+=w2*bflo(v.x); a[1]+=w2*bfhi(v.x); a[2]+=w2*bflo(v.y); a[3]+=w2*bfhi(v.y);
        a[4]+=w2*bflo(v.z); a[5]+=w2*bfhi(v.z); a[6]+=w2*bflo(v.w); a[7]+=w2*bfhi(v.w);
      }
      if (s3 >= 0){
        uint4 v = hb4[(size_t)s3*4 + li];
        a[0]+=w3*bflo(v.x); a[1]+=w3*bfhi(v.x); a[2]+=w3*bflo(v.y); a[3]+=w3*bfhi(v.y);
        a[4]+=w3*bflo(v.z); a[5]+=w3*bfhi(v.z); a[6]+=w3*bflo(v.w); a[7]+=w3*bfhi(v.w);
      }
    }
  }
  l += __shfl_xor(l,2); l += __shfl_xor(l,4); l += __shfl_xor(l,8);
  l += __shfl_xor(l,16); l += __shfl_xor(l,32);
  #pragma unroll
  for (int msk=4; msk<64; msk<<=1){
    #pragma unroll
    for (int k=0;k<8;k++) a[k] += __shfl_xor(a[k], msk);
  }
  float denom = __shfl(l, ghead);
  float invh = 1.f/denom;
  float r0_ = eluf(a[0]*invh + bias[li*8+0]);
  float r1_ = eluf(a[1]*invh + bias[li*8+1]);
  float r2_ = eluf(a[2]*invh + bias[li*8+2]);
  float r3_ = eluf(a[3]*invh + bias[li*8+3]);
  float r4_ = eluf(a[4]*invh + bias[li*8+4]);
  float r5_ = eluf(a[5]*invh + bias[li*8+5]);
  float r6_ = eluf(a[6]*invh + bias[li*8+6]);
  float r7_ = eluf(a[7]*invh + bias[li*8+7]);
  const float* wr = &W3[li*16];
  float p0 = r0_*wr[0] + r1_*wr[2] + r2_*wr[4]  + r3_*wr[6]
           + r4_*wr[8] + r5_*wr[10]+ r6_*wr[12] + r7_*wr[14];
  float p1 = r0_*wr[1] + r1_*wr[3] + r2_*wr[5]  + r3_*wr[7]
           + r4_*wr[9] + r5_*wr[11]+ r6_*wr[13] + r7_*wr[15];
  p0 += __shfl_xor(p0,1); p0 += __shfl_xor(p0,2);
  p1 += __shfl_xor(p1,1); p1 += __shfl_xor(p1,2);
  if (lane == 0){
    float4 pk;
    pk.x = p0; pk.y = p1;
    pk.z = p0*atts3[0] + p1*atts3[1];   // as3
    pk.w = p0*attd3[0] + p1*attd3[1];   // ad3
    pk4[n] = pk;
  }
}

// Layer 3: packed gather — one float4 (h0,h1,as3,ad3) load per edge.
__global__ __launch_bounds__(256) void k_agg3(const int* __restrict__ rp, const int* __restrict__ csr,
    const float4* __restrict__ pk4, const float* __restrict__ bias,
    float* __restrict__ out, int N){
  int n = blockIdx.x*4 + (threadIdx.x>>6);
  if (n >= N) return;
  int lane = threadIdx.x & 63;
  int start = rp[n], end = rp[n+1];
  float4 self = pk4[n];
  float adh = self.w;
  float sl = lrelu(self.z + adh);
  float l = 0.f;
  float2 acc = make_float2(0.f, 0.f);
  for (int i=start+lane; i<end; i+=64){
    int s = csr[i];
    float4 ps = pk4[s];
    float w = __expf(fminf(lrelu(ps.z + adh), 80.f));
    l += w;
    acc.x += w*ps.x; acc.y += w*ps.y;
  }
  if (lane == 0){
    float w = __expf(fminf(sl, 80.f));
    l += w;
    acc.x += w*self.x; acc.y += w*self.y;
  }
  l = wred_sum(l);
  acc.x = wred_sum(acc.x); acc.y = wred_sum(acc.y);
  if (lane == 0){
    float inv = 1.f/l;
    float g0 = acc.x*inv + bias[0];
    float g1 = acc.y*inv + bias[1];
    float mm = fmaxf(g0, g1);
    float lse = mm + logf(__expf(g0-mm) + __expf(g1-mm));
    *(float2*)&out[2*n] = make_float2(g0-lse, g1-lse);
  }
}

// ---------------- launch ----------------
extern "C" void kernel_launch(void* const* d_in, const int* in_sizes, int n_in,
                              void* d_out, int out_size, void* d_ws, size_t ws_size,
                              hipStream_t stream) {
  const float* x   = (const float*)d_in[0];
  const void*  ei  = d_in[1];
  const float* W1  = (const float*)d_in[2];
  const float* as1 = (const float*)d_in[3];
  const float* ad1 = (const float*)d_in[4];
  const float* b1  = (const float*)d_in[5];
  const float* W2  = (const float*)d_in[6];
  const float* as2 = (const float*)d_in[7];
  const float* ad2 = (const float*)d_in[8];
  const float* b2  = (const float*)d_in[9];
  const float* W3  = (const float*)d_in[10];
  const float* as3 = (const float*)d_in[11];
  const float* ad3 = (const float*)d_in[12];
  const float* b3  = (const float*)d_in[13];

  int N = in_sizes[0] / 128;
  int E = in_sizes[1] / 2;
  int NB = (N + 127) >> 7;           // 128 dst per bucket

  char* w = (char*)d_ws;
  size_t off = 0;
  auto alloc = [&](size_t bytes)->void*{
    void* p = w + off; off += (bytes + 255) & ~(size_t)255; return p;
  };
  int*   gbcnt   = (int*)alloc((size_t)NB*4);
  int*   gbbase  = (int*)alloc((size_t)NB*4);
  int*   gcursor = (int*)alloc((size_t)NB*4);
  int*   rp      = (int*)alloc((size_t)(N+1)*4);
  unsigned int* ebuf = (unsigned int*)alloc((size_t)E*4);
  int*   csr     = (int*)alloc((size_t)E*4);
  float* as_buf  = (float*)alloc((size_t)N*4*4);
  float* ad_buf  = (float*)alloc((size_t)N*4*4);
  float* as2_buf = (float*)alloc((size_t)N*2*4);
  float* ad2_buf = (float*)alloc((size_t)N*2*4);
  unsigned short* wf1 = (unsigned short*)alloc(2048*8*2);        // W1 frags bf16
  unsigned short* hb  = (unsigned short*)alloc((size_t)N*128*2); // layer1 h bf16
  unsigned short* hb2 = (unsigned short*)alloc((size_t)N*32*2);  // layer2 h bf16
  float4* pk4    = (float4*)alloc((size_t)N*16);                 // packed (h3,as3,ad3)
  if (off > ws_size) return;  // workspace too small -> visible failure

  hipMemsetAsync(gbcnt, 0, (size_t)NB*4, stream);
  k_wprep<<<8, 256, 0, stream>>>(W1, wf1);
  k_bhist<<<256, 256, NB*4, stream>>>(ei, gbcnt, E, NB);
  k_bscan<<<1, 256, 0, stream>>>(gbcnt, gbbase, gcursor, NB);

  // FUSED: CSR scatter (GS blocks) || layer-1 MFMA GEMM (G1 blocks)
  int GS = (E + 256*BS_ITEMS - 1) / (256*BS_ITEMS);
  int G1 = (N + 63)/64;
  k_scat_gemm1<<<GS + G1, 256, 0, stream>>>(ei, gcursor, ebuf, E, NB, GS,
                                            x, wf1, as1, ad1, hb, as_buf, ad_buf, N);
  k_bcsr<<<NB, 256, 0, stream>>>(ebuf, gbbase, gbcnt, rp, csr, N, NB, E);

  // layer 1 aggregation + fused layer-2 GEMM + layer-2 att terms
  k_agg1<<<(N + 3)/4, 256, 0, stream>>>(rp, csr, as_buf, ad_buf, (const uint4*)hb, b1,
                                        W2, as2, ad2, hb2, as2_buf, ad2_buf, N);

  // layer 2 aggregation + fused layer-3 GEMM (packed output)
  k_agg2<<<(N + 3)/4, 256, 0, stream>>>(rp, csr, as2_buf, ad2_buf, (const uint4*)hb2, b2,
                                        W3, as3, ad3, pk4, N);

  // layer 3: packed gather + bias + log_softmax
  k_agg3<<<(N + 3)/4, 256, 0, stream>>>(rp, csr, pk4, b3, (float*)d_out, N);
}

// Round 11
// 355.926 us; speedup vs baseline: 1.3621x; 1.3621x over previous
//
#include <hip/hip_runtime.h>
#include <math.h>

// ---------------- helpers ----------------
static __device__ __forceinline__ float lrelu(float x){ return fmaxf(x, 0.2f*x); }
static __device__ __forceinline__ float eluf(float x){ return x > 0.f ? x : __expf(x)-1.f; }
static __device__ __forceinline__ float wred_sum(float v){
  v += __shfl_xor(v, 32); v += __shfl_xor(v, 16); v += __shfl_xor(v, 8);
  v += __shfl_xor(v, 4);  v += __shfl_xor(v, 2);  v += __shfl_xor(v, 1);
  return v;
}
static __device__ __forceinline__ unsigned short f2bf(float f){
  unsigned int u = __float_as_uint(f);
  unsigned int r = (u + 0x7FFFu + ((u>>16)&1u)) >> 16;   // round-nearest-even
  return (unsigned short)r;
}
static __device__ __forceinline__ float bflo(unsigned int u){ return __uint_as_float(u<<16); }
static __device__ __forceinline__ float bfhi(unsigned int u){ return __uint_as_float(u & 0xFFFF0000u); }

typedef __attribute__((ext_vector_type(8))) short short8;   // 8 bf16 = 4 VGPR
typedef __attribute__((ext_vector_type(4))) float f32x4;

// ---------------- bucketed CSR build (bucket = dst>>7) ----------------
#define DETECT_IS64(ei_, s_is64_) \
  if (threadIdx.x < 64){ \
    int w_ = ((const int*)(ei_))[2*threadIdx.x + 1]; \
    unsigned long long b_ = __ballot(w_ != 0); \
    if (threadIdx.x == 0) s_is64_ = (b_ == 0ull); \
  } \
  __syncthreads();

__global__ __launch_bounds__(256) void k_bhist(const void* __restrict__ ei,
    int* __restrict__ gbcnt, int E, int NB){
  extern __shared__ int lcnt[];
  __shared__ int s_is64;
  for (int i=threadIdx.x; i<NB; i+=256) lcnt[i]=0;
  DETECT_IS64(ei, s_is64)
  int stride = gridDim.x*256;
  if (s_is64){
    const long long* p = (const long long*)ei;
    for (int e = blockIdx.x*256 + threadIdx.x; e < E; e += stride)
      atomicAdd(&lcnt[((int)p[(size_t)E+e])>>7], 1);
  } else {
    const int* p = (const int*)ei;
    for (int e = blockIdx.x*256 + threadIdx.x; e < E; e += stride)
      atomicAdd(&lcnt[p[(size_t)E+e]>>7], 1);
  }
  __syncthreads();
  for (int i=threadIdx.x; i<NB; i+=256){
    int c = lcnt[i];
    if (c) atomicAdd(&gbcnt[i], c);
  }
}

__global__ __launch_bounds__(256) void k_bscan(const int* __restrict__ gbcnt,
    int* __restrict__ gbbase, int* __restrict__ gcursor, int NB){
  __shared__ int sh[256];
  __shared__ int carry;
  int t = threadIdx.x;
  if (t==0) carry = 0;
  __syncthreads();
  for (int base=0; base<NB; base+=256){
    int idx = base+t;
    int v = (idx<NB)? gbcnt[idx] : 0;
    sh[t]=v; __syncthreads();
    for (int off=1; off<256; off<<=1){
      int add = (t>=off)? sh[t-off] : 0;
      __syncthreads();
      sh[t]+=add;
      __syncthreads();
    }
    int excl = sh[t]-v+carry;
    if (idx<NB){ gbbase[idx]=excl; gcursor[idx]=excl; }
    __syncthreads();
    if (t==0) carry += sh[255];
    __syncthreads();
  }
}

// ---- FUSED: bscatter (blocks [0,GS)) || mgemm1 (blocks [GS, GS+G1)) -------
#define BS_ITEMS 16
__global__ __launch_bounds__(256) void k_scat_gemm1(
    const void* __restrict__ ei, int* __restrict__ gcursor,
    unsigned int* __restrict__ ebuf, int E, int NB, int GS,
    const float* __restrict__ x, const unsigned short* __restrict__ wf,
    const float* __restrict__ atts, const float* __restrict__ attd,
    unsigned short* __restrict__ hb, float* __restrict__ as_, float* __restrict__ ad_,
    int N){
  __shared__ __align__(16) unsigned char smem[50176];
  __shared__ int s_is64;
  int t = threadIdx.x;
  if ((int)blockIdx.x < GS){
    // ---------------- scatter role ----------------
    int* lcnt  = (int*)smem;
    int* lbase = lcnt + NB;
    for (int i=t; i<NB; i+=256) lcnt[i]=0;
    DETECT_IS64(ei, s_is64)
    bool is64 = s_is64 != 0;
    int base = blockIdx.x*(256*BS_ITEMS);
    unsigned int ent[BS_ITEMS]; int bk[BS_ITEMS];
    #pragma unroll
    for (int i=0;i<BS_ITEMS;i++){
      int e = base + i*256 + t;
      if (e < E){
        int s, d;
        if (is64){ const long long* p=(const long long*)ei; s=(int)p[e]; d=(int)p[(size_t)E+e]; }
        else     { const int* p=(const int*)ei;            s=p[e];      d=p[(size_t)E+e]; }
        int b = d>>7;
        bk[i] = b;
        ent[i] = (unsigned int)s | ((unsigned int)(d & 127) << 25);
        atomicAdd(&lcnt[b], 1);
      } else bk[i] = -1;
    }
    __syncthreads();
    for (int i=t; i<NB; i+=256){
      int c = lcnt[i];
      lbase[i] = c ? atomicAdd(&gcursor[i], c) : 0;
    }
    __syncthreads();
    for (int i=t; i<NB; i+=256) lcnt[i]=0;  // reuse as cursor
    __syncthreads();
    #pragma unroll
    for (int i=0;i<BS_ITEMS;i++){
      if (bk[i] >= 0){
        int pos = lbase[bk[i]] + atomicAdd(&lcnt[bk[i]], 1);
        ebuf[pos] = ent[i];
      }
    }
  } else {
    // ---------------- mgemm1 role ----------------
    unsigned short* xs  = (unsigned short*)smem;              // 64*136
    unsigned short* wsm = (unsigned short*)(smem + 64*136*2); // 2048*8
    int r0 = ((int)blockIdx.x - GS)*64;
    { // stage W frags: 2048 uint4 (32 KB)
      const uint4* src = (const uint4*)wf;
      uint4* dst = (uint4*)wsm;
      #pragma unroll
      for (int i=0;i<8;i++) dst[t + i*256] = src[t + i*256];
    }
    { // stage x tile (fp32 -> bf16)
      #pragma unroll
      for (int i=0;i<4;i++){
        int idx = t + i*256;
        int row = idx>>4, k8 = (idx&15)*8;
        int gr = r0 + row;
        float4 v0 = make_float4(0.f,0.f,0.f,0.f), v1 = v0;
        if (gr < N){
          v0 = *(const float4*)&x[(size_t)gr*128 + k8];
          v1 = *(const float4*)&x[(size_t)gr*128 + k8 + 4];
        }
        union { unsigned short us[8]; uint4 u; } pk;
        pk.us[0]=f2bf(v0.x); pk.us[1]=f2bf(v0.y); pk.us[2]=f2bf(v0.z); pk.us[3]=f2bf(v0.w);
        pk.us[4]=f2bf(v1.x); pk.us[5]=f2bf(v1.y); pk.us[6]=f2bf(v1.z); pk.us[7]=f2bf(v1.w);
        *(uint4*)&xs[row*136 + k8] = pk.u;
      }
    }
    __syncthreads();
    int w = t>>6, lane = t&63, lm = lane&15, q = lane>>4;
    int rt0 = (w&1)*2;
    int ct0 = (w>>1)*4;
    f32x4 acc[2][4];
    #pragma unroll
    for (int a=0;a<2;a++)
      #pragma unroll
      for (int c=0;c<4;c++) acc[a][c] = (f32x4){0.f,0.f,0.f,0.f};
    #pragma unroll
    for (int ks=0;ks<4;ks++){
      short8 a0 = *(const short8*)&xs[( rt0   *16 + lm)*136 + ks*32 + q*8];
      short8 a1 = *(const short8*)&xs[((rt0+1)*16 + lm)*136 + ks*32 + q*8];
      #pragma unroll
      for (int c=0;c<4;c++){
        short8 b = *(const short8*)&wsm[((ks*8 + ct0 + c)*64 + lane)*8];
        acc[0][c] = __builtin_amdgcn_mfma_f32_16x16x32_bf16(a0, b, acc[0][c], 0,0,0);
        acc[1][c] = __builtin_amdgcn_mfma_f32_16x16x32_bf16(a1, b, acc[1][c], 0,0,0);
      }
    }
    __syncthreads();   // xs becomes C-tile
    // C/D layout: col = lane&15, row = (lane>>4)*4 + reg (guide §3, m89/m91)
    #pragma unroll
    for (int rl=0;rl<2;rl++)
      #pragma unroll
      for (int c=0;c<4;c++)
        #pragma unroll
        for (int r=0;r<4;r++)
          xs[((rt0+rl)*16 + q*4 + r)*136 + (ct0+c)*16 + lm] = f2bf(acc[rl][c][r]);
    __syncthreads();
    { // hb writes
      #pragma unroll
      for (int i=0;i<4;i++){
        int idx = t + i*256;
        int row = idx>>4, c8 = (idx&15)*8;
        int gr = r0 + row;
        if (gr < N)
          *(uint4*)&hb[(size_t)gr*128 + c8] = *(const uint4*)&xs[row*136 + c8];
      }
    }
    { // fused attention dots
      int row = t>>2, h = t&3;
      int gr = r0 + row;
      if (gr < N){
        const unsigned short* hr = &xs[row*136 + h*32];
        const float* sa = atts + h*32;
        const float* da = attd + h*32;
        float ss = 0.f, dd = 0.f;
        #pragma unroll
        for (int o=0;o<32;o+=8){
          uint4 v = *(const uint4*)&hr[o];
          float hv[8] = { bflo(v.x),bfhi(v.x),bflo(v.y),bfhi(v.y),
                          bflo(v.z),bfhi(v.z),bflo(v.w),bfhi(v.w) };
          #pragma unroll
          for (int m=0;m<8;m++){ ss += hv[m]*sa[o+m]; dd += hv[m]*da[o+m]; }
        }
        as_[gr*4+h] = ss; ad_[gr*4+h] = dd;
      }
    }
  }
}

__global__ __launch_bounds__(256) void k_bcsr(const unsigned int* __restrict__ ebuf,
    const int* __restrict__ gbbase, const int* __restrict__ gbcnt,
    int* __restrict__ rp, int* __restrict__ csr, int N, int NB, int E){
  __shared__ int lcnt[128];
  __shared__ int lexc[128];
  __shared__ int lcur[128];
  __shared__ int sc[256];
  int b = blockIdx.x, t = threadIdx.x;
  int d0 = b<<7;
  int R = N - d0; if (R > 128) R = 128;
  if (t < 128){ lcnt[t]=0; lcur[t]=0; }
  __syncthreads();
  int base = gbbase[b], cnt = gbcnt[b];
  for (int i=t; i<cnt; i+=256){
    unsigned int e = ebuf[base+i];
    atomicAdd(&lcnt[e>>25], 1);
  }
  __syncthreads();
  int v = (t<128)? lcnt[t] : 0;
  sc[t]=v; __syncthreads();
  for (int off=1; off<128; off<<=1){
    int add = (t>=off)? sc[t-off] : 0;
    __syncthreads();
    sc[t]+=add;
    __syncthreads();
  }
  if (t<128) lexc[t] = sc[t]-v;
  __syncthreads();
  if (t < R) rp[d0+t] = base + lexc[t];
  if (b == NB-1 && t == 0) rp[N] = E;
  for (int i=t; i<cnt; i+=256){
    unsigned int e = ebuf[base+i];
    int dl = e>>25;
    int pos = base + lexc[dl] + atomicAdd(&lcur[dl], 1);
    csr[pos] = (int)(e & 0x1FFFFFFu);
  }
}

// ------- W pre-pack into MFMA B-fragment order (bf16), once per call -------
// B-frag (16x16x32): lane l holds B[k = (l>>4)*8 + j][n = l&15], j=0..7.
__global__ void k_wprep(const float* __restrict__ W1, const float* __restrict__ W2,
                        unsigned short* __restrict__ wf1, unsigned short* __restrict__ wf2){
  int e = blockIdx.x*256 + threadIdx.x;
  if (e < 2048){
    int lane = e&63, ct = (e>>6)&7, ks = e>>9;
    int q = lane>>4, n = lane&15;
    union { unsigned short us[8]; uint4 u; } pk;
    #pragma unroll
    for (int j=0;j<8;j++)
      pk.us[j] = f2bf(W1[(ks*32 + q*8 + j)*128 + ct*16 + n]);
    *(uint4*)&wf1[(size_t)e*8] = pk.u;
  } else if (e < 2048+512){
    int e2 = e - 2048;
    int lane = e2&63, ct = (e2>>6)&1, ks = e2>>7;
    int q = lane>>4, n = lane&15;
    union { unsigned short us[8]; uint4 u; } pk;
    #pragma unroll
    for (int j=0;j<8;j++)
      pk.us[j] = f2bf(W2[(ks*32 + q*8 + j)*32 + ct*16 + n]);
    *(uint4*)&wf2[(size_t)e2*8] = pk.u;
  }
}

// ------- GEMM2 (MFMA): xb bf16 @ W2 -> hb2 bf16, + fused att dots ----------
// NOTE (R10 post-mortem): this MFMA kernel with LDS-staged, lane-uniform W2
// reads is the right home for GEMM2. Fusing it into agg1's epilogue with
// per-lane scattered W2 reads quadrupled the TA line traffic of a gather-
// bound kernel (82 -> 235 us). Keep GEMM2 separate.
__global__ __launch_bounds__(256) void k_mgemm2(const unsigned short* __restrict__ xb,
    const unsigned short* __restrict__ wf,
    const float* __restrict__ atts, const float* __restrict__ attd,
    unsigned short* __restrict__ hb2, float* __restrict__ as_, float* __restrict__ ad_,
    int N){
  __shared__ unsigned short xs[128*136];   // 34 KB: x-tile, later C-tile
  __shared__ unsigned short wsm[512*8];    // 8 KB: W2 fragments
  int t = threadIdx.x;
  int r0 = blockIdx.x*128;
  { // stage W frags: 512 uint4 (8 KB)
    #pragma unroll
    for (int i=0;i<2;i++)
      ((uint4*)wsm)[t + i*256] = ((const uint4*)wf)[t + i*256];
  }
  { // stage x tile (already bf16): 128 rows x 16 uint4
    #pragma unroll
    for (int i=0;i<8;i++){
      int idx = t + i*256;
      int row = idx>>4, c8 = (idx&15)*8;
      int gr = r0 + row;
      uint4 v = make_uint4(0u,0u,0u,0u);
      if (gr < N) v = *(const uint4*)&xb[(size_t)gr*128 + c8];
      *(uint4*)&xs[row*136 + c8] = v;
    }
  }
  __syncthreads();
  int w = t>>6, lane = t&63, lm = lane&15, q = lane>>4;
  int rt0 = 2*w;
  f32x4 acc[2][2];
  #pragma unroll
  for (int a=0;a<2;a++){ acc[a][0] = (f32x4){0.f,0.f,0.f,0.f}; acc[a][1] = acc[a][0]; }
  #pragma unroll
  for (int ks=0;ks<4;ks++){
    short8 a0 = *(const short8*)&xs[( rt0   *16 + lm)*136 + ks*32 + q*8];
    short8 a1 = *(const short8*)&xs[((rt0+1)*16 + lm)*136 + ks*32 + q*8];
    #pragma unroll
    for (int c=0;c<2;c++){
      short8 b = *(const short8*)&wsm[((ks*2 + c)*64 + lane)*8];
      acc[0][c] = __builtin_amdgcn_mfma_f32_16x16x32_bf16(a0, b, acc[0][c], 0,0,0);
      acc[1][c] = __builtin_amdgcn_mfma_f32_16x16x32_bf16(a1, b, acc[1][c], 0,0,0);
    }
  }
  __syncthreads();
  #pragma unroll
  for (int rl=0;rl<2;rl++)
    #pragma unroll
    for (int c=0;c<2;c++)
      #pragma unroll
      for (int r=0;r<4;r++)
        xs[((rt0+rl)*16 + q*4 + r)*136 + c*16 + lm] = f2bf(acc[rl][c][r]);
  __syncthreads();
  { // hb2 writes: 128 rows x 4 uint4
    #pragma unroll
    for (int i=0;i<2;i++){
      int idx = t + i*256;
      int row = idx>>2, c8 = (idx&3)*8;
      int gr = r0 + row;
      if (gr < N)
        *(uint4*)&hb2[(size_t)gr*32 + c8] = *(const uint4*)&xs[row*136 + c8];
    }
  }
  { // fused attention dots: 128 rows x 2 heads = 256 pairs
    int row = t>>1, h = t&1;
    int gr = r0 + row;
    if (gr < N){
      const unsigned short* hr = &xs[row*136 + h*16];
      const float* sa = atts + h*16;
      const float* da = attd + h*16;
      float ss = 0.f, dd = 0.f;
      #pragma unroll
      for (int o=0;o<16;o+=8){
        uint4 v = *(const uint4*)&hr[o];
        float hv[8] = { bflo(v.x),bfhi(v.x),bflo(v.y),bfhi(v.y),
                        bflo(v.z),bfhi(v.z),bflo(v.w),bfhi(v.w) };
        #pragma unroll
        for (int m=0;m<8;m++){ ss += hv[m]*sa[o+m]; dd += hv[m]*da[o+m]; }
      }
      as_[gr*2+h] = ss; ad_[gr*2+h] = dd;
    }
  }
}

// ---------------- aggregation: single pass, exp-deduplicated --------------
// Layer 1: H=4,O=32. 32 edges/iter, 8 gathers in flight. Writes xb bf16.
__global__ __launch_bounds__(256) void k_agg1(const int* __restrict__ rp, const int* __restrict__ csr,
    const float* __restrict__ as_, const float* __restrict__ ad_,
    const uint4* __restrict__ hb4, const float* __restrict__ bias,
    unsigned short* __restrict__ outb, int N){
  int n = blockIdx.x*4 + (threadIdx.x>>6);
  if (n >= N) return;
  int lane = threadIdx.x & 63;
  int eslot = lane>>2, ehead = lane&3;       // exp duty: 16 edge-slots x 4 heads
  int grp = lane>>4, li = lane&15, ghead = li>>2;  // gather duty
  int start = rp[n], end = rp[n+1];
  float adh_e = ad_[n*4+ehead];
  float w_self_e = __expf(fminf(lrelu(as_[n*4+ehead] + adh_e), 80.f));
  float l = (eslot == 0) ? w_self_e : 0.f;
  float a[8];
  #pragma unroll
  for (int k=0;k<8;k++) a[k]=0.f;
  { // self-loop row first
    float w = __shfl(w_self_e, ghead);
    if (grp == 0){
      uint4 v = hb4[(size_t)n*16 + li];
      a[0]+=w*bflo(v.x); a[1]+=w*bfhi(v.x); a[2]+=w*bflo(v.y); a[3]+=w*bfhi(v.y);
      a[4]+=w*bflo(v.z); a[5]+=w*bfhi(v.z); a[6]+=w*bflo(v.w); a[7]+=w*bfhi(v.w);
    }
  }
  for (int i0 = start; i0 < end; i0 += 32){
    int ei0 = i0 + eslot, ei1 = i0 + 16 + eslot;
    int s0 = -1, s1 = -1; float w0 = 0.f, w1 = 0.f;
    if (ei0 < end){
      s0 = csr[ei0];
      w0 = __expf(fminf(lrelu(as_[s0*4+ehead] + adh_e), 80.f));
      l += w0;
    }
    if (ei1 < end){
      s1 = csr[ei1];
      w1 = __expf(fminf(lrelu(as_[s1*4+ehead] + adh_e), 80.f));
      l += w1;
    }
    #pragma unroll
    for (int r=0;r<4;r++){
      int srclane = ((r*4+grp)<<2) | ghead;
      int   s2 = __shfl(s0, srclane);
      float w2 = __shfl(w0, srclane);
      int   s3 = __shfl(s1, srclane);
      float w3 = __shfl(w1, srclane);
      if (s2 >= 0){
        uint4 v = hb4[(size_t)s2*16 + li];
        a[0]+=w2*bflo(v.x); a[1]+=w2*bfhi(v.x); a[2]+=w2*bflo(v.y); a[3]+=w2*bfhi(v.y);
        a[4]+=w2*bflo(v.z); a[5]+=w2*bfhi(v.z); a[6]+=w2*bflo(v.w); a[7]+=w2*bfhi(v.w);
      }
      if (s3 >= 0){
        uint4 v = hb4[(size_t)s3*16 + li];
        a[0]+=w3*bflo(v.x); a[1]+=w3*bfhi(v.x); a[2]+=w3*bflo(v.y); a[3]+=w3*bfhi(v.y);
        a[4]+=w3*bflo(v.z); a[5]+=w3*bfhi(v.z); a[6]+=w3*bflo(v.w); a[7]+=w3*bfhi(v.w);
      }
    }
  }
  l += __shfl_xor(l,4); l += __shfl_xor(l,8); l += __shfl_xor(l,16); l += __shfl_xor(l,32);
  #pragma unroll
  for (int msk=16; msk<64; msk<<=1){
    #pragma unroll
    for (int k=0;k<8;k++) a[k] += __shfl_xor(a[k], msk);
  }
  float denom = __shfl(l, ghead);
  if (grp == 0){
    float invh = 1.f/denom;
    float4 b0 = *(const float4*)&bias[li*8];
    float4 b1 = *(const float4*)&bias[li*8+4];
    union { unsigned short us[8]; uint4 v; } pk;
    pk.us[0]=f2bf(eluf(a[0]*invh+b0.x)); pk.us[1]=f2bf(eluf(a[1]*invh+b0.y));
    pk.us[2]=f2bf(eluf(a[2]*invh+b0.z)); pk.us[3]=f2bf(eluf(a[3]*invh+b0.w));
    pk.us[4]=f2bf(eluf(a[4]*invh+b1.x)); pk.us[5]=f2bf(eluf(a[5]*invh+b1.y));
    pk.us[6]=f2bf(eluf(a[6]*invh+b1.z)); pk.us[7]=f2bf(eluf(a[7]*invh+b1.w));
    *(uint4*)&outb[(size_t)n*128 + li*8] = pk.v;
  }
}

// Layer 2: H=2,O=16. 64 edges/iter, exp-dedup. Fused layer-3 GEMM epilogue;
// writes packed float4(h3.x, h3.y, as3, ad3) so agg3 gathers ONE 16B load/edge.
__global__ __launch_bounds__(256) void k_agg2(const int* __restrict__ rp, const int* __restrict__ csr,
    const float* __restrict__ as_, const float* __restrict__ ad_,
    const uint4* __restrict__ hb4, const float* __restrict__ bias,
    const float* __restrict__ W3, const float* __restrict__ atts3,
    const float* __restrict__ attd3,
    float4* __restrict__ pk4, int N){
  int n = blockIdx.x*4 + (threadIdx.x>>6);
  if (n >= N) return;
  int lane = threadIdx.x & 63;
  int eslot = lane>>1, ehead = lane&1;       // 32 edge-slots x 2 heads
  int grp = lane>>2, li = lane&3, ghead = li>>1;
  int start = rp[n], end = rp[n+1];
  float adh_e = ad_[n*2+ehead];
  float w_self_e = __expf(fminf(lrelu(as_[n*2+ehead] + adh_e), 80.f));
  float l = (eslot == 0) ? w_self_e : 0.f;
  float a[8];
  #pragma unroll
  for (int k=0;k<8;k++) a[k]=0.f;
  { // self-loop row first
    float w = __shfl(w_self_e, ghead);
    if (grp == 0){
      uint4 v = hb4[(size_t)n*4 + li];
      a[0]+=w*bflo(v.x); a[1]+=w*bfhi(v.x); a[2]+=w*bflo(v.y); a[3]+=w*bfhi(v.y);
      a[4]+=w*bflo(v.z); a[5]+=w*bfhi(v.z); a[6]+=w*bflo(v.w); a[7]+=w*bfhi(v.w);
    }
  }
  for (int i0 = start; i0 < end; i0 += 64){
    int ei0 = i0 + eslot, ei1 = i0 + 32 + eslot;
    int s0 = -1, s1 = -1; float w0 = 0.f, w1 = 0.f;
    if (ei0 < end){
      s0 = csr[ei0];
      w0 = __expf(fminf(lrelu(as_[s0*2+ehead] + adh_e), 80.f));
      l += w0;
    }
    if (ei1 < end){
      s1 = csr[ei1];
      w1 = __expf(fminf(lrelu(as_[s1*2+ehead] + adh_e), 80.f));
      l += w1;
    }
    #pragma unroll
    for (int r=0;r<2;r++){
      int srclane = ((r*16+grp)<<1) | ghead;
      int   s2 = __shfl(s0, srclane);
      float w2 = __shfl(w0, srclane);
      int   s3 = __shfl(s1, srclane);
      float w3 = __shfl(w1, srclane);
      if (s2 >= 0){
        uint4 v = hb4[(size_t)s2*4 + li];
        a[0]+=w2*bflo(v.x); a[1]+=w2*bfhi(v.x); a[2]+=w2*bflo(v.y); a[3]+=w2*bfhi(v.y);
        a[4]+=w2*bflo(v.z); a[5]+=w2*bfhi(v.z); a[6]+=w2*bflo(v.w); a[7]+=w2*bfhi(v.w);
      }
      if (s3 >= 0){
        uint4 v = hb4[(size_t)s3*4 + li];
        a[0]+=w3*bflo(v.x); a[1]+=w3*bfhi(v.x); a[2]+=w3*bflo(v.y); a[3]+=w3*bfhi(v.y);
        a[4]+=w3*bflo(v.z); a[5]+=w3*bfhi(v.z); a[6]+=w3*bflo(v.w); a[7]+=w3*bfhi(v.w);
      }
    }
  }
  l += __shfl_xor(l,2); l += __shfl_xor(l,4); l += __shfl_xor(l,8);
  l += __shfl_xor(l,16); l += __shfl_xor(l,32);
  #pragma unroll
  for (int msk=4; msk<64; msk<<=1){
    #pragma unroll
    for (int k=0;k<8;k++) a[k] += __shfl_xor(a[k], msk);
  }
  float denom = __shfl(l, ghead);
  float invh = 1.f/denom;
  float r0_ = eluf(a[0]*invh + bias[li*8+0]);
  float r1_ = eluf(a[1]*invh + bias[li*8+1]);
  float r2_ = eluf(a[2]*invh + bias[li*8+2]);
  float r3_ = eluf(a[3]*invh + bias[li*8+3]);
  float r4_ = eluf(a[4]*invh + bias[li*8+4]);
  float r5_ = eluf(a[5]*invh + bias[li*8+5]);
  float r6_ = eluf(a[6]*invh + bias[li*8+6]);
  float r7_ = eluf(a[7]*invh + bias[li*8+7]);
  const float* wr = &W3[li*16];
  float p0 = r0_*wr[0] + r1_*wr[2] + r2_*wr[4]  + r3_*wr[6]
           + r4_*wr[8] + r5_*wr[10]+ r6_*wr[12] + r7_*wr[14];
  float p1 = r0_*wr[1] + r1_*wr[3] + r2_*wr[5]  + r3_*wr[7]
           + r4_*wr[9] + r5_*wr[11]+ r6_*wr[13] + r7_*wr[15];
  p0 += __shfl_xor(p0,1); p0 += __shfl_xor(p0,2);
  p1 += __shfl_xor(p1,1); p1 += __shfl_xor(p1,2);
  if (lane == 0){
    float4 pk;
    pk.x = p0; pk.y = p1;
    pk.z = p0*atts3[0] + p1*atts3[1];   // as3
    pk.w = p0*attd3[0] + p1*attd3[1];   // ad3
    pk4[n] = pk;
  }
}

// Layer 3: packed gather — one float4 (h0,h1,as3,ad3) load per edge.
__global__ __launch_bounds__(256) void k_agg3(const int* __restrict__ rp, const int* __restrict__ csr,
    const float4* __restrict__ pk4, const float* __restrict__ bias,
    float* __restrict__ out, int N){
  int n = blockIdx.x*4 + (threadIdx.x>>6);
  if (n >= N) return;
  int lane = threadIdx.x & 63;
  int start = rp[n], end = rp[n+1];
  float4 self = pk4[n];
  float adh = self.w;
  float sl = lrelu(self.z + adh);
  float l = 0.f;
  float2 acc = make_float2(0.f, 0.f);
  for (int i=start+lane; i<end; i+=64){
    int s = csr[i];
    float4 ps = pk4[s];
    float w = __expf(fminf(lrelu(ps.z + adh), 80.f));
    l += w;
    acc.x += w*ps.x; acc.y += w*ps.y;
  }
  if (lane == 0){
    float w = __expf(fminf(sl, 80.f));
    l += w;
    acc.x += w*self.x; acc.y += w*self.y;
  }
  l = wred_sum(l);
  acc.x = wred_sum(acc.x); acc.y = wred_sum(acc.y);
  if (lane == 0){
    float inv = 1.f/l;
    float g0 = acc.x*inv + bias[0];
    float g1 = acc.y*inv + bias[1];
    float mm = fmaxf(g0, g1);
    float lse = mm + logf(__expf(g0-mm) + __expf(g1-mm));
    *(float2*)&out[2*n] = make_float2(g0-lse, g1-lse);
  }
}

// ---------------- launch ----------------
extern "C" void kernel_launch(void* const* d_in, const int* in_sizes, int n_in,
                              void* d_out, int out_size, void* d_ws, size_t ws_size,
                              hipStream_t stream) {
  const float* x   = (const float*)d_in[0];
  const void*  ei  = d_in[1];
  const float* W1  = (const float*)d_in[2];
  const float* as1 = (const float*)d_in[3];
  const float* ad1 = (const float*)d_in[4];
  const float* b1  = (const float*)d_in[5];
  const float* W2  = (const float*)d_in[6];
  const float* as2 = (const float*)d_in[7];
  const float* ad2 = (const float*)d_in[8];
  const float* b2  = (const float*)d_in[9];
  const float* W3  = (const float*)d_in[10];
  const float* as3 = (const float*)d_in[11];
  const float* ad3 = (const float*)d_in[12];
  const float* b3  = (const float*)d_in[13];

  int N = in_sizes[0] / 128;
  int E = in_sizes[1] / 2;
  int NB = (N + 127) >> 7;           // 128 dst per bucket

  char* w = (char*)d_ws;
  size_t off = 0;
  auto alloc = [&](size_t bytes)->void*{
    void* p = w + off; off += (bytes + 255) & ~(size_t)255; return p;
  };
  int*   gbcnt   = (int*)alloc((size_t)NB*4);
  int*   gbbase  = (int*)alloc((size_t)NB*4);
  int*   gcursor = (int*)alloc((size_t)NB*4);
  int*   rp      = (int*)alloc((size_t)(N+1)*4);
  unsigned int* ebuf = (unsigned int*)alloc((size_t)E*4);
  int*   csr     = (int*)alloc((size_t)E*4);
  float* as_buf  = (float*)alloc((size_t)N*4*4);
  float* ad_buf  = (float*)alloc((size_t)N*4*4);
  unsigned short* wf1 = (unsigned short*)alloc(2048*8*2);        // W1 frags bf16
  unsigned short* wf2 = (unsigned short*)alloc(512*8*2);         // W2 frags bf16
  unsigned short* hb  = (unsigned short*)alloc((size_t)N*128*2); // layer1 h bf16
  unsigned short* xb  = (unsigned short*)alloc((size_t)N*128*2); // layer1 out bf16
  unsigned short* hb2 = (unsigned short*)alloc((size_t)N*32*2);  // layer2 h bf16
  float4* pk4    = (float4*)alloc((size_t)N*16);                 // packed (h3,as3,ad3)
  if (off > ws_size) return;  // workspace too small -> visible failure

  hipMemsetAsync(gbcnt, 0, (size_t)NB*4, stream);
  k_wprep<<<10, 256, 0, stream>>>(W1, W2, wf1, wf2);
  k_bhist<<<256, 256, NB*4, stream>>>(ei, gbcnt, E, NB);
  k_bscan<<<1, 256, 0, stream>>>(gbcnt, gbbase, gcursor, NB);

  // FUSED: CSR scatter (GS blocks) || layer-1 MFMA GEMM (G1 blocks)
  int GS = (E + 256*BS_ITEMS - 1) / (256*BS_ITEMS);
  int G1 = (N + 63)/64;
  k_scat_gemm1<<<GS + G1, 256, 0, stream>>>(ei, gcursor, ebuf, E, NB, GS,
                                            x, wf1, as1, ad1, hb, as_buf, ad_buf, N);
  k_bcsr<<<NB, 256, 0, stream>>>(ebuf, gbbase, gbcnt, rp, csr, N, NB, E);

  // layer 1 aggregation -> xb
  k_agg1<<<(N + 3)/4, 256, 0, stream>>>(rp, csr, as_buf, ad_buf, (const uint4*)hb, b1, xb, N);

  // layer 2: MFMA GEMM + fused att epilogue (as_buf/ad_buf reused for H=2 terms)
  k_mgemm2<<<(N + 127)/128, 256, 0, stream>>>(xb, wf2, as2, ad2, hb2, as_buf, ad_buf, N);
  // agg2 with fused layer-3 GEMM epilogue -> packed pk4
  k_agg2<<<(N + 3)/4, 256, 0, stream>>>(rp, csr, as_buf, ad_buf, (const uint4*)hb2, b2,
                                        W3, as3, ad3, pk4, N);

  // layer 3: packed gather + bias + log_softmax
  k_agg3<<<(N + 3)/4, 256, 0, stream>>>(rp, csr, pk4, b3, (float*)d_out, N);
}

// Round 12
// 350.388 us; speedup vs baseline: 1.3836x; 1.0158x over previous
//
#include <hip/hip_runtime.h>
#include <math.h>

// ---------------- helpers ----------------
static __device__ __forceinline__ float lrelu(float x){ return fmaxf(x, 0.2f*x); }
static __device__ __forceinline__ float eluf(float x){ return x > 0.f ? x : __expf(x)-1.f; }
static __device__ __forceinline__ unsigned short f2bf(float f){
  unsigned int u = __float_as_uint(f);
  unsigned int r = (u + 0x7FFFu + ((u>>16)&1u)) >> 16;   // round-nearest-even
  return (unsigned short)r;
}
static __device__ __forceinline__ float bflo(unsigned int u){ return __uint_as_float(u<<16); }
static __device__ __forceinline__ float bfhi(unsigned int u){ return __uint_as_float(u & 0xFFFF0000u); }

typedef __attribute__((ext_vector_type(8))) short short8;   // 8 bf16 = 4 VGPR
typedef __attribute__((ext_vector_type(4))) float f32x4;

#define DETECT_IS64(ei_, s_is64_) \
  if (threadIdx.x < 64){ \
    int w_ = ((const int*)(ei_))[2*threadIdx.x + 1]; \
    unsigned long long b_ = __ballot(w_ != 0); \
    if (threadIdx.x == 0) s_is64_ = (b_ == 0ull); \
  } \
  __syncthreads();

// ------- W pre-pack into MFMA B-frag order + zero gbcnt/done (1st kernel) --
// B-frag (16x16x32): lane l holds B[k = (l>>4)*8 + j][n = l&15], j=0..7.
__global__ void k_wprep(const float* __restrict__ W1, const float* __restrict__ W2,
                        unsigned short* __restrict__ wf1, unsigned short* __restrict__ wf2,
                        int* __restrict__ gbcnt, int* __restrict__ done, int NB){
  int e = blockIdx.x*256 + threadIdx.x;
  if (e < NB) gbcnt[e] = 0;
  if (e == 0) *done = 0;
  if (e < 2048){
    int lane = e&63, ct = (e>>6)&7, ks = e>>9;
    int q = lane>>4, n = lane&15;
    union { unsigned short us[8]; uint4 u; } pk;
    #pragma unroll
    for (int j=0;j<8;j++)
      pk.us[j] = f2bf(W1[(ks*32 + q*8 + j)*128 + ct*16 + n]);
    *(uint4*)&wf1[(size_t)e*8] = pk.u;
  } else if (e < 2048+512){
    int e2 = e - 2048;
    int lane = e2&63, ct = (e2>>6)&1, ks = e2>>7;
    int q = lane>>4, n = lane&15;
    union { unsigned short us[8]; uint4 u; } pk;
    #pragma unroll
    for (int j=0;j<8;j++)
      pk.us[j] = f2bf(W2[(ks*32 + q*8 + j)*32 + ct*16 + n]);
    *(uint4*)&wf2[(size_t)e2*8] = pk.u;
  }
}

// ------- bhist + (last-block) exclusive scan, merged -----------------------
// Each block histograms into LDS, flushes via device-scope atomics, then
// bumps a done counter (after threadfence). The LAST block re-reads gbcnt
// with atomicAdd(p,0) (device-scope; dodges stale per-XCD L2 lines, G16)
// and performs the 782-entry exclusive scan -> gbbase/gcursor.
__global__ __launch_bounds__(256) void k_bhist_scan(const void* __restrict__ ei,
    int* __restrict__ gbcnt, int* __restrict__ gbbase, int* __restrict__ gcursor,
    int* __restrict__ done, int E, int NB){
  extern __shared__ int lcnt[];
  __shared__ int s_is64;
  __shared__ int s_last;
  __shared__ int sh[256];
  __shared__ int carry;
  int t = threadIdx.x;
  for (int i=t; i<NB; i+=256) lcnt[i]=0;
  DETECT_IS64(ei, s_is64)
  int stride = gridDim.x*256;
  if (s_is64){
    const long long* p = (const long long*)ei;
    for (int e = blockIdx.x*256 + t; e < E; e += stride)
      atomicAdd(&lcnt[((int)p[(size_t)E+e])>>7], 1);
  } else {
    const int* p = (const int*)ei;
    for (int e = blockIdx.x*256 + t; e < E; e += stride)
      atomicAdd(&lcnt[p[(size_t)E+e]>>7], 1);
  }
  __syncthreads();
  for (int i=t; i<NB; i+=256){
    int c = lcnt[i];
    if (c) atomicAdd(&gbcnt[i], c);
  }
  __threadfence();
  if (t == 0){
    int old = atomicAdd(done, 1);
    s_last = (old == (int)gridDim.x - 1) ? 1 : 0;
  }
  __syncthreads();
  if (!s_last) return;
  // ---- scan tail (one block) ----
  if (t==0) carry = 0;
  __syncthreads();
  for (int base=0; base<NB; base+=256){
    int idx = base+t;
    int v = (idx<NB) ? atomicAdd(&gbcnt[idx], 0) : 0;
    sh[t]=v; __syncthreads();
    for (int off=1; off<256; off<<=1){
      int add = (t>=off)? sh[t-off] : 0;
      __syncthreads();
      sh[t]+=add;
      __syncthreads();
    }
    int excl = sh[t]-v+carry;
    if (idx<NB){ gbbase[idx]=excl; gcursor[idx]=excl; }
    __syncthreads();
    if (t==0) carry += sh[255];
    __syncthreads();
  }
}

// ---- FUSED: bscatter (blocks [0,GS)) || mgemm1 (blocks [GS, GS+G1)) -------
#define BS_ITEMS 16
__global__ __launch_bounds__(256) void k_scat_gemm1(
    const void* __restrict__ ei, int* __restrict__ gcursor,
    unsigned int* __restrict__ ebuf, int E, int NB, int GS,
    const float* __restrict__ x, const unsigned short* __restrict__ wf,
    const float* __restrict__ atts, const float* __restrict__ attd,
    unsigned short* __restrict__ hb, float* __restrict__ as_, float* __restrict__ ad_,
    int N){
  __shared__ __align__(16) unsigned char smem[50176];
  __shared__ int s_is64;
  int t = threadIdx.x;
  if ((int)blockIdx.x < GS){
    // ---------------- scatter role ----------------
    int* lcnt  = (int*)smem;
    int* lbase = lcnt + NB;
    for (int i=t; i<NB; i+=256) lcnt[i]=0;
    DETECT_IS64(ei, s_is64)
    bool is64 = s_is64 != 0;
    int base = blockIdx.x*(256*BS_ITEMS);
    unsigned int ent[BS_ITEMS]; int bk[BS_ITEMS];
    #pragma unroll
    for (int i=0;i<BS_ITEMS;i++){
      int e = base + i*256 + t;
      if (e < E){
        int s, d;
        if (is64){ const long long* p=(const long long*)ei; s=(int)p[e]; d=(int)p[(size_t)E+e]; }
        else     { const int* p=(const int*)ei;            s=p[e];      d=p[(size_t)E+e]; }
        int b = d>>7;
        bk[i] = b;
        ent[i] = (unsigned int)s | ((unsigned int)(d & 127) << 25);
        atomicAdd(&lcnt[b], 1);
      } else bk[i] = -1;
    }
    __syncthreads();
    for (int i=t; i<NB; i+=256){
      int c = lcnt[i];
      lbase[i] = c ? atomicAdd(&gcursor[i], c) : 0;
    }
    __syncthreads();
    for (int i=t; i<NB; i+=256) lcnt[i]=0;  // reuse as cursor
    __syncthreads();
    #pragma unroll
    for (int i=0;i<BS_ITEMS;i++){
      if (bk[i] >= 0){
        int pos = lbase[bk[i]] + atomicAdd(&lcnt[bk[i]], 1);
        ebuf[pos] = ent[i];
      }
    }
  } else {
    // ---------------- mgemm1 role ----------------
    unsigned short* xs  = (unsigned short*)smem;              // 64*136
    unsigned short* wsm = (unsigned short*)(smem + 64*136*2); // 2048*8
    int r0 = ((int)blockIdx.x - GS)*64;
    { // stage W frags: 2048 uint4 (32 KB)
      const uint4* src = (const uint4*)wf;
      uint4* dst = (uint4*)wsm;
      #pragma unroll
      for (int i=0;i<8;i++) dst[t + i*256] = src[t + i*256];
    }
    { // stage x tile (fp32 -> bf16)
      #pragma unroll
      for (int i=0;i<4;i++){
        int idx = t + i*256;
        int row = idx>>4, k8 = (idx&15)*8;
        int gr = r0 + row;
        float4 v0 = make_float4(0.f,0.f,0.f,0.f), v1 = v0;
        if (gr < N){
          v0 = *(const float4*)&x[(size_t)gr*128 + k8];
          v1 = *(const float4*)&x[(size_t)gr*128 + k8 + 4];
        }
        union { unsigned short us[8]; uint4 u; } pk;
        pk.us[0]=f2bf(v0.x); pk.us[1]=f2bf(v0.y); pk.us[2]=f2bf(v0.z); pk.us[3]=f2bf(v0.w);
        pk.us[4]=f2bf(v1.x); pk.us[5]=f2bf(v1.y); pk.us[6]=f2bf(v1.z); pk.us[7]=f2bf(v1.w);
        *(uint4*)&xs[row*136 + k8] = pk.u;
      }
    }
    __syncthreads();
    int w = t>>6, lane = t&63, lm = lane&15, q = lane>>4;
    int rt0 = (w&1)*2;
    int ct0 = (w>>1)*4;
    f32x4 acc[2][4];
    #pragma unroll
    for (int a=0;a<2;a++)
      #pragma unroll
      for (int c=0;c<4;c++) acc[a][c] = (f32x4){0.f,0.f,0.f,0.f};
    #pragma unroll
    for (int ks=0;ks<4;ks++){
      short8 a0 = *(const short8*)&xs[( rt0   *16 + lm)*136 + ks*32 + q*8];
      short8 a1 = *(const short8*)&xs[((rt0+1)*16 + lm)*136 + ks*32 + q*8];
      #pragma unroll
      for (int c=0;c<4;c++){
        short8 b = *(const short8*)&wsm[((ks*8 + ct0 + c)*64 + lane)*8];
        acc[0][c] = __builtin_amdgcn_mfma_f32_16x16x32_bf16(a0, b, acc[0][c], 0,0,0);
        acc[1][c] = __builtin_amdgcn_mfma_f32_16x16x32_bf16(a1, b, acc[1][c], 0,0,0);
      }
    }
    __syncthreads();   // xs becomes C-tile
    // C/D layout: col = lane&15, row = (lane>>4)*4 + reg (guide §3, m89/m91)
    #pragma unroll
    for (int rl=0;rl<2;rl++)
      #pragma unroll
      for (int c=0;c<4;c++)
        #pragma unroll
        for (int r=0;r<4;r++)
          xs[((rt0+rl)*16 + q*4 + r)*136 + (ct0+c)*16 + lm] = f2bf(acc[rl][c][r]);
    __syncthreads();
    { // hb writes
      #pragma unroll
      for (int i=0;i<4;i++){
        int idx = t + i*256;
        int row = idx>>4, c8 = (idx&15)*8;
        int gr = r0 + row;
        if (gr < N)
          *(uint4*)&hb[(size_t)gr*128 + c8] = *(const uint4*)&xs[row*136 + c8];
      }
    }
    { // fused attention dots
      int row = t>>2, h = t&3;
      int gr = r0 + row;
      if (gr < N){
        const unsigned short* hr = &xs[row*136 + h*32];
        const float* sa = atts + h*32;
        const float* da = attd + h*32;
        float ss = 0.f, dd = 0.f;
        #pragma unroll
        for (int o=0;o<32;o+=8){
          uint4 v = *(const uint4*)&hr[o];
          float hv[8] = { bflo(v.x),bfhi(v.x),bflo(v.y),bfhi(v.y),
                          bflo(v.z),bfhi(v.z),bflo(v.w),bfhi(v.w) };
          #pragma unroll
          for (int m=0;m<8;m++){ ss += hv[m]*sa[o+m]; dd += hv[m]*da[o+m]; }
        }
        as_[gr*4+h] = ss; ad_[gr*4+h] = dd;
      }
    }
  }
}

__global__ __launch_bounds__(256) void k_bcsr(const unsigned int* __restrict__ ebuf,
    const int* __restrict__ gbbase, const int* __restrict__ gbcnt,
    int* __restrict__ rp, int* __restrict__ csr, int N, int NB, int E){
  __shared__ int lcnt[128];
  __shared__ int lexc[128];
  __shared__ int lcur[128];
  __shared__ int sc[256];
  int b = blockIdx.x, t = threadIdx.x;
  int d0 = b<<7;
  int R = N - d0; if (R > 128) R = 128;
  if (t < 128){ lcnt[t]=0; lcur[t]=0; }
  __syncthreads();
  int base = gbbase[b], cnt = gbcnt[b];
  for (int i=t; i<cnt; i+=256){
    unsigned int e = ebuf[base+i];
    atomicAdd(&lcnt[e>>25], 1);
  }
  __syncthreads();
  int v = (t<128)? lcnt[t] : 0;
  sc[t]=v; __syncthreads();
  for (int off=1; off<128; off<<=1){
    int add = (t>=off)? sc[t-off] : 0;
    __syncthreads();
    sc[t]+=add;
    __syncthreads();
  }
  if (t<128) lexc[t] = sc[t]-v;
  __syncthreads();
  if (t < R) rp[d0+t] = base + lexc[t];
  if (b == NB-1 && t == 0) rp[N] = E;
  for (int i=t; i<cnt; i+=256){
    unsigned int e = ebuf[base+i];
    int dl = e>>25;
    int pos = base + lexc[dl] + atomicAdd(&lcur[dl], 1);
    csr[pos] = (int)(e & 0x1FFFFFFu);
  }
}

// ------- GEMM2 (MFMA): xb bf16 @ W2 -> hb2 bf16, + fused att dots ----------
// NOTE (R10): keep GEMM2 as a separate MFMA kernel with LDS-staged W2 —
// fusing scattered W2 reads into gather-bound agg1 cost 82 -> 235 us.
__global__ __launch_bounds__(256) void k_mgemm2(const unsigned short* __restrict__ xb,
    const unsigned short* __restrict__ wf,
    const float* __restrict__ atts, const float* __restrict__ attd,
    unsigned short* __restrict__ hb2, float* __restrict__ as_, float* __restrict__ ad_,
    int N){
  __shared__ unsigned short xs[128*136];   // 34 KB: x-tile, later C-tile
  __shared__ unsigned short wsm[512*8];    // 8 KB: W2 fragments
  int t = threadIdx.x;
  int r0 = blockIdx.x*128;
  {
    #pragma unroll
    for (int i=0;i<2;i++)
      ((uint4*)wsm)[t + i*256] = ((const uint4*)wf)[t + i*256];
  }
  {
    #pragma unroll
    for (int i=0;i<8;i++){
      int idx = t + i*256;
      int row = idx>>4, c8 = (idx&15)*8;
      int gr = r0 + row;
      uint4 v = make_uint4(0u,0u,0u,0u);
      if (gr < N) v = *(const uint4*)&xb[(size_t)gr*128 + c8];
      *(uint4*)&xs[row*136 + c8] = v;
    }
  }
  __syncthreads();
  int w = t>>6, lane = t&63, lm = lane&15, q = lane>>4;
  int rt0 = 2*w;
  f32x4 acc[2][2];
  #pragma unroll
  for (int a=0;a<2;a++){ acc[a][0] = (f32x4){0.f,0.f,0.f,0.f}; acc[a][1] = acc[a][0]; }
  #pragma unroll
  for (int ks=0;ks<4;ks++){
    short8 a0 = *(const short8*)&xs[( rt0   *16 + lm)*136 + ks*32 + q*8];
    short8 a1 = *(const short8*)&xs[((rt0+1)*16 + lm)*136 + ks*32 + q*8];
    #pragma unroll
    for (int c=0;c<2;c++){
      short8 b = *(const short8*)&wsm[((ks*2 + c)*64 + lane)*8];
      acc[0][c] = __builtin_amdgcn_mfma_f32_16x16x32_bf16(a0, b, acc[0][c], 0,0,0);
      acc[1][c] = __builtin_amdgcn_mfma_f32_16x16x32_bf16(a1, b, acc[1][c], 0,0,0);
    }
  }
  __syncthreads();
  #pragma unroll
  for (int rl=0;rl<2;rl++)
    #pragma unroll
    for (int c=0;c<2;c++)
      #pragma unroll
      for (int r=0;r<4;r++)
        xs[((rt0+rl)*16 + q*4 + r)*136 + c*16 + lm] = f2bf(acc[rl][c][r]);
  __syncthreads();
  {
    #pragma unroll
    for (int i=0;i<2;i++){
      int idx = t + i*256;
      int row = idx>>2, c8 = (idx&3)*8;
      int gr = r0 + row;
      if (gr < N)
        *(uint4*)&hb2[(size_t)gr*32 + c8] = *(const uint4*)&xs[row*136 + c8];
    }
  }
  {
    int row = t>>1, h = t&1;
    int gr = r0 + row;
    if (gr < N){
      const unsigned short* hr = &xs[row*136 + h*16];
      const float* sa = atts + h*16;
      const float* da = attd + h*16;
      float ss = 0.f, dd = 0.f;
      #pragma unroll
      for (int o=0;o<16;o+=8){
        uint4 v = *(const uint4*)&hr[o];
        float hv[8] = { bflo(v.x),bfhi(v.x),bflo(v.y),bfhi(v.y),
                        bflo(v.z),bfhi(v.z),bflo(v.w),bfhi(v.w) };
        #pragma unroll
        for (int m=0;m<8;m++){ ss += hv[m]*sa[o+m]; dd += hv[m]*da[o+m]; }
      }
      as_[gr*2+h] = ss; ad_[gr*2+h] = dd;
    }
  }
}

// ---------------- aggregation: single pass, exp-deduplicated --------------
// Layer 1: H=4,O=32. 32 edges/iter, 8 gathers in flight. Writes xb bf16.
__global__ __launch_bounds__(256) void k_agg1(const int* __restrict__ rp, const int* __restrict__ csr,
    const float* __restrict__ as_, const float* __restrict__ ad_,
    const uint4* __restrict__ hb4, const float* __restrict__ bias,
    unsigned short* __restrict__ outb, int N){
  int n = blockIdx.x*4 + (threadIdx.x>>6);
  if (n >= N) return;
  int lane = threadIdx.x & 63;
  int eslot = lane>>2, ehead = lane&3;       // exp duty: 16 edge-slots x 4 heads
  int grp = lane>>4, li = lane&15, ghead = li>>2;  // gather duty
  int start = rp[n], end = rp[n+1];
  float adh_e = ad_[n*4+ehead];
  float w_self_e = __expf(fminf(lrelu(as_[n*4+ehead] + adh_e), 80.f));
  float l = (eslot == 0) ? w_self_e : 0.f;
  float a[8];
  #pragma unroll
  for (int k=0;k<8;k++) a[k]=0.f;
  { // self-loop row first
    float w = __shfl(w_self_e, ghead);
    if (grp == 0){
      uint4 v = hb4[(size_t)n*16 + li];
      a[0]+=w*bflo(v.x); a[1]+=w*bfhi(v.x); a[2]+=w*bflo(v.y); a[3]+=w*bfhi(v.y);
      a[4]+=w*bflo(v.z); a[5]+=w*bfhi(v.z); a[6]+=w*bflo(v.w); a[7]+=w*bfhi(v.w);
    }
  }
  for (int i0 = start; i0 < end; i0 += 32){
    int ei0 = i0 + eslot, ei1 = i0 + 16 + eslot;
    int s0 = -1, s1 = -1; float w0 = 0.f, w1 = 0.f;
    if (ei0 < end){
      s0 = csr[ei0];
      w0 = __expf(fminf(lrelu(as_[s0*4+ehead] + adh_e), 80.f));
      l += w0;
    }
    if (ei1 < end){
      s1 = csr[ei1];
      w1 = __expf(fminf(lrelu(as_[s1*4+ehead] + adh_e), 80.f));
      l += w1;
    }
    #pragma unroll
    for (int r=0;r<4;r++){
      int srclane = ((r*4+grp)<<2) | ghead;
      int   s2 = __shfl(s0, srclane);
      float w2 = __shfl(w0, srclane);
      int   s3 = __shfl(s1, srclane);
      float w3 = __shfl(w1, srclane);
      if (s2 >= 0){
        uint4 v = hb4[(size_t)s2*16 + li];
        a[0]+=w2*bflo(v.x); a[1]+=w2*bfhi(v.x); a[2]+=w2*bflo(v.y); a[3]+=w2*bfhi(v.y);
        a[4]+=w2*bflo(v.z); a[5]+=w2*bfhi(v.z); a[6]+=w2*bflo(v.w); a[7]+=w2*bfhi(v.w);
      }
      if (s3 >= 0){
        uint4 v = hb4[(size_t)s3*16 + li];
        a[0]+=w3*bflo(v.x); a[1]+=w3*bfhi(v.x); a[2]+=w3*bflo(v.y); a[3]+=w3*bfhi(v.y);
        a[4]+=w3*bflo(v.z); a[5]+=w3*bfhi(v.z); a[6]+=w3*bflo(v.w); a[7]+=w3*bfhi(v.w);
      }
    }
  }
  l += __shfl_xor(l,4); l += __shfl_xor(l,8); l += __shfl_xor(l,16); l += __shfl_xor(l,32);
  #pragma unroll
  for (int msk=16; msk<64; msk<<=1){
    #pragma unroll
    for (int k=0;k<8;k++) a[k] += __shfl_xor(a[k], msk);
  }
  float denom = __shfl(l, ghead);
  if (grp == 0){
    float invh = 1.f/denom;
    float4 b0 = *(const float4*)&bias[li*8];
    float4 b1 = *(const float4*)&bias[li*8+4];
    union { unsigned short us[8]; uint4 v; } pk;
    pk.us[0]=f2bf(eluf(a[0]*invh+b0.x)); pk.us[1]=f2bf(eluf(a[1]*invh+b0.y));
    pk.us[2]=f2bf(eluf(a[2]*invh+b0.z)); pk.us[3]=f2bf(eluf(a[3]*invh+b0.w));
    pk.us[4]=f2bf(eluf(a[4]*invh+b1.x)); pk.us[5]=f2bf(eluf(a[5]*invh+b1.y));
    pk.us[6]=f2bf(eluf(a[6]*invh+b1.z)); pk.us[7]=f2bf(eluf(a[7]*invh+b1.w));
    *(uint4*)&outb[(size_t)n*128 + li*8] = pk.v;
  }
}

// Layer 2: H=2,O=16. 64 edges/iter, exp-dedup. Fused layer-3 GEMM epilogue;
// writes packed float4(h3.x, h3.y, as3, ad3) so agg3 gathers ONE 16B load/edge.
__global__ __launch_bounds__(256) void k_agg2(const int* __restrict__ rp, const int* __restrict__ csr,
    const float* __restrict__ as_, const float* __restrict__ ad_,
    const uint4* __restrict__ hb4, const float* __restrict__ bias,
    const float* __restrict__ W3, const float* __restrict__ atts3,
    const float* __restrict__ attd3,
    float4* __restrict__ pk4, int N){
  int n = blockIdx.x*4 + (threadIdx.x>>6);
  if (n >= N) return;
  int lane = threadIdx.x & 63;
  int eslot = lane>>1, ehead = lane&1;       // 32 edge-slots x 2 heads
  int grp = lane>>2, li = lane&3, ghead = li>>1;
  int start = rp[n], end = rp[n+1];
  float adh_e = ad_[n*2+ehead];
  float w_self_e = __expf(fminf(lrelu(as_[n*2+ehead] + adh_e), 80.f));
  float l = (eslot == 0) ? w_self_e : 0.f;
  float a[8];
  #pragma unroll
  for (int k=0;k<8;k++) a[k]=0.f;
  { // self-loop row first
    float w = __shfl(w_self_e, ghead);
    if (grp == 0){
      uint4 v = hb4[(size_t)n*4 + li];
      a[0]+=w*bflo(v.x); a[1]+=w*bfhi(v.x); a[2]+=w*bflo(v.y); a[3]+=w*bfhi(v.y);
      a[4]+=w*bflo(v.z); a[5]+=w*bfhi(v.z); a[6]+=w*bflo(v.w); a[7]+=w*bfhi(v.w);
    }
  }
  for (int i0 = start; i0 < end; i0 += 64){
    int ei0 = i0 + eslot, ei1 = i0 + 32 + eslot;
    int s0 = -1, s1 = -1; float w0 = 0.f, w1 = 0.f;
    if (ei0 < end){
      s0 = csr[ei0];
      w0 = __expf(fminf(lrelu(as_[s0*2+ehead] + adh_e), 80.f));
      l += w0;
    }
    if (ei1 < end){
      s1 = csr[ei1];
      w1 = __expf(fminf(lrelu(as_[s1*2+ehead] + adh_e), 80.f));
      l += w1;
    }
    #pragma unroll
    for (int r=0;r<2;r++){
      int srclane = ((r*16+grp)<<1) | ghead;
      int   s2 = __shfl(s0, srclane);
      float w2 = __shfl(w0, srclane);
      int   s3 = __shfl(s1, srclane);
      float w3 = __shfl(w1, srclane);
      if (s2 >= 0){
        uint4 v = hb4[(size_t)s2*4 + li];
        a[0]+=w2*bflo(v.x); a[1]+=w2*bfhi(v.x); a[2]+=w2*bflo(v.y); a[3]+=w2*bfhi(v.y);
        a[4]+=w2*bflo(v.z); a[5]+=w2*bfhi(v.z); a[6]+=w2*bflo(v.w); a[7]+=w2*bfhi(v.w);
      }
      if (s3 >= 0){
        uint4 v = hb4[(size_t)s3*4 + li];
        a[0]+=w3*bflo(v.x); a[1]+=w3*bfhi(v.x); a[2]+=w3*bflo(v.y); a[3]+=w3*bfhi(v.y);
        a[4]+=w3*bflo(v.z); a[5]+=w3*bfhi(v.z); a[6]+=w3*bflo(v.w); a[7]+=w3*bfhi(v.w);
      }
    }
  }
  l += __shfl_xor(l,2); l += __shfl_xor(l,4); l += __shfl_xor(l,8);
  l += __shfl_xor(l,16); l += __shfl_xor(l,32);
  #pragma unroll
  for (int msk=4; msk<64; msk<<=1){
    #pragma unroll
    for (int k=0;k<8;k++) a[k] += __shfl_xor(a[k], msk);
  }
  float denom = __shfl(l, ghead);
  float invh = 1.f/denom;
  float r0_ = eluf(a[0]*invh + bias[li*8+0]);
  float r1_ = eluf(a[1]*invh + bias[li*8+1]);
  float r2_ = eluf(a[2]*invh + bias[li*8+2]);
  float r3_ = eluf(a[3]*invh + bias[li*8+3]);
  float r4_ = eluf(a[4]*invh + bias[li*8+4]);
  float r5_ = eluf(a[5]*invh + bias[li*8+5]);
  float r6_ = eluf(a[6]*invh + bias[li*8+6]);
  float r7_ = eluf(a[7]*invh + bias[li*8+7]);
  const float* wr = &W3[li*16];
  float p0 = r0_*wr[0] + r1_*wr[2] + r2_*wr[4]  + r3_*wr[6]
           + r4_*wr[8] + r5_*wr[10]+ r6_*wr[12] + r7_*wr[14];
  float p1 = r0_*wr[1] + r1_*wr[3] + r2_*wr[5]  + r3_*wr[7]
           + r4_*wr[9] + r5_*wr[11]+ r6_*wr[13] + r7_*wr[15];
  p0 += __shfl_xor(p0,1); p0 += __shfl_xor(p0,2);
  p1 += __shfl_xor(p1,1); p1 += __shfl_xor(p1,2);
  if (lane == 0){
    float4 pk;
    pk.x = p0; pk.y = p1;
    pk.z = p0*atts3[0] + p1*atts3[1];   // as3
    pk.w = p0*attd3[0] + p1*attd3[1];   // ad3
    pk4[n] = pk;
  }
}

// Layer 3: 16 lanes per node (4 nodes/wave, 16/block) — one float4 gather
// per edge per lane; group-local xor reduction (masks 1..8 stay in-group).
__global__ __launch_bounds__(256) void k_agg3(const int* __restrict__ rp, const int* __restrict__ csr,
    const float4* __restrict__ pk4, const float* __restrict__ bias,
    float* __restrict__ out, int N){
  int n = blockIdx.x*16 + (threadIdx.x>>4);
  if (n >= N) return;
  int li = threadIdx.x & 15;
  int start = rp[n], end = rp[n+1];
  float4 self = pk4[n];
  float adh = self.w;
  float l = 0.f;
  float2 acc = make_float2(0.f, 0.f);
  for (int i=start+li; i<end; i+=16){
    int s = csr[i];
    float4 ps = pk4[s];
    float w = __expf(fminf(lrelu(ps.z + adh), 80.f));
    l += w;
    acc.x += w*ps.x; acc.y += w*ps.y;
  }
  if (li == 0){
    float w = __expf(fminf(lrelu(self.z + adh), 80.f));
    l += w;
    acc.x += w*self.x; acc.y += w*self.y;
  }
  #pragma unroll
  for (int msk=1; msk<16; msk<<=1){
    l += __shfl_xor(l, msk);
    acc.x += __shfl_xor(acc.x, msk);
    acc.y += __shfl_xor(acc.y, msk);
  }
  if (li == 0){
    float inv = 1.f/l;
    float g0 = acc.x*inv + bias[0];
    float g1 = acc.y*inv + bias[1];
    float mm = fmaxf(g0, g1);
    float lse = mm + logf(__expf(g0-mm) + __expf(g1-mm));
    *(float2*)&out[2*n] = make_float2(g0-lse, g1-lse);
  }
}

// ---------------- launch ----------------
extern "C" void kernel_launch(void* const* d_in, const int* in_sizes, int n_in,
                              void* d_out, int out_size, void* d_ws, size_t ws_size,
                              hipStream_t stream) {
  const float* x   = (const float*)d_in[0];
  const void*  ei  = d_in[1];
  const float* W1  = (const float*)d_in[2];
  const float* as1 = (const float*)d_in[3];
  const float* ad1 = (const float*)d_in[4];
  const float* b1  = (const float*)d_in[5];
  const float* W2  = (const float*)d_in[6];
  const float* as2 = (const float*)d_in[7];
  const float* ad2 = (const float*)d_in[8];
  const float* b2  = (const float*)d_in[9];
  const float* W3  = (const float*)d_in[10];
  const float* as3 = (const float*)d_in[11];
  const float* ad3 = (const float*)d_in[12];
  const float* b3  = (const float*)d_in[13];

  int N = in_sizes[0] / 128;
  int E = in_sizes[1] / 2;
  int NB = (N + 127) >> 7;           // 128 dst per bucket

  char* w = (char*)d_ws;
  size_t off = 0;
  auto alloc = [&](size_t bytes)->void*{
    void* p = w + off; off += (bytes + 255) & ~(size_t)255; return p;
  };
  int*   gbcnt   = (int*)alloc((size_t)NB*4);
  int*   gbbase  = (int*)alloc((size_t)NB*4);
  int*   gcursor = (int*)alloc((size_t)NB*4);
  int*   done    = (int*)alloc(256);
  int*   rp      = (int*)alloc((size_t)(N+1)*4);
  unsigned int* ebuf = (unsigned int*)alloc((size_t)E*4);
  int*   csr     = (int*)alloc((size_t)E*4);
  float* as_buf  = (float*)alloc((size_t)N*4*4);
  float* ad_buf  = (float*)alloc((size_t)N*4*4);
  unsigned short* wf1 = (unsigned short*)alloc(2048*8*2);        // W1 frags bf16
  unsigned short* wf2 = (unsigned short*)alloc(512*8*2);         // W2 frags bf16
  unsigned short* hb  = (unsigned short*)alloc((size_t)N*128*2); // layer1 h bf16
  unsigned short* xb  = (unsigned short*)alloc((size_t)N*128*2); // layer1 out bf16
  unsigned short* hb2 = (unsigned short*)alloc((size_t)N*32*2);  // layer2 h bf16
  float4* pk4    = (float4*)alloc((size_t)N*16);                 // packed (h3,as3,ad3)
  if (off > ws_size) return;  // workspace too small -> visible failure

  // 1) W prep + gbcnt/done zeroing (replaces hipMemsetAsync)
  k_wprep<<<10, 256, 0, stream>>>(W1, W2, wf1, wf2, gbcnt, done, NB);
  // 2) bucket histogram + last-block exclusive scan (merged bhist+bscan)
  k_bhist_scan<<<256, 256, NB*4, stream>>>(ei, gbcnt, gbbase, gcursor, done, E, NB);

  // 3) FUSED: CSR scatter (GS blocks) || layer-1 MFMA GEMM (G1 blocks)
  int GS = (E + 256*BS_ITEMS - 1) / (256*BS_ITEMS);
  int G1 = (N + 63)/64;
  k_scat_gemm1<<<GS + G1, 256, 0, stream>>>(ei, gcursor, ebuf, E, NB, GS,
                                            x, wf1, as1, ad1, hb, as_buf, ad_buf, N);
  // 4) per-bucket CSR finalize
  k_bcsr<<<NB, 256, 0, stream>>>(ebuf, gbbase, gbcnt, rp, csr, N, NB, E);

  // 5) layer 1 aggregation -> xb
  k_agg1<<<(N + 3)/4, 256, 0, stream>>>(rp, csr, as_buf, ad_buf, (const uint4*)hb, b1, xb, N);

  // 6) layer 2: MFMA GEMM + fused att epilogue
  k_mgemm2<<<(N + 127)/128, 256, 0, stream>>>(xb, wf2, as2, ad2, hb2, as_buf, ad_buf, N);
  // 7) agg2 with fused layer-3 GEMM epilogue -> packed pk4
  k_agg2<<<(N + 3)/4, 256, 0, stream>>>(rp, csr, as_buf, ad_buf, (const uint4*)hb2, b2,
                                        W3, as3, ad3, pk4, N);

  // 8) layer 3: packed gather + bias + log_softmax (16 lanes/node)
  k_agg3<<<(N + 15)/16, 256, 0, stream>>>(rp, csr, pk4, b3, (float*)d_out, N);
}